// Round 7
// baseline (257.784 us; speedup 1.0000x reference)
//
#include <hip/hip_runtime.h>

// EquivariantProductBasisBlock (MACE symmetric contraction, corr=3) + o3.Linear
// N=10000 nodes, C=128 channels, L=9 (lmax=2), E=5 elements, fp32 throughout.
//
// R20 changes vs R19 (linear only; sort/table/contract frozen):
//  - R19 post-mortem: 313-block grid -> 4.9 waves/CU (Occupancy 10%); the
//    8-chunk vmcnt(0)+barrier chain ran unoverlapped; 961K bank-conflict
//    cycles on W LDS reads. Four rounds of evidence: LDS pipe and per-lane
//    VMEM both can't feed this GEMM; the scalar (SMEM) path can.
//  - linear rewrite: wave = (16 c1 outputs, 1 dd), lane = node. dd/c1-group
//    readfirstlane'd -> W row slices wave-uniform -> s_load to SGPRs (the
//    contract trick). A = tmp[dd][ci][p]: per-lane coalesced dwords.
//    Per ci: 1 VMEM dword + 16 SGPR-operand FMA. 628 blocks x 8 waves =
//    5024 waves (~20/CU), VGPR ~40 -> 8 waves/SIMD hides L1 latency.
//    LDS only in epilogue (SROW[64][132], pad kills column conflicts),
//    flushed as two contiguous spans per node (y0 + interleaved-y1).

#define CCH 128
#define LDIM 9
#define NE 5
#define BLK 256
#define TSTR 220             // coeffs per (e,c,dd): 219 + 1 pad (16B-aligned)
#define TGSTR 880            // per (e,c) = 4*TSTR
#define U3LDS 8748           // staged U3 slice (729*12 max)

// -------------------------------------------- sort: count + offs (fused)
__global__ __launch_bounds__(BLK) void count_offs_kernel(
    const float* __restrict__ attrs, int N,
    int* __restrict__ elem, int* __restrict__ gcnt,   // gcnt[5], gcnt[5]=done
    int* __restrict__ offs, int* __restrict__ cur) {
  int n = blockIdx.x * BLK + threadIdx.x;
  int e = 0;
  if (n < N) {
    const float* a = attrs + n * NE;
#pragma unroll
    for (int j = 1; j < NE; ++j)
      if (a[j] > 0.5f) e = j;
    elem[n] = e;
  }
  int lane = threadIdx.x & 63;
#pragma unroll
  for (int k = 0; k < NE; ++k) {
    unsigned long long m = __ballot(n < N && e == k);
    if (m) {
      int leader = __ffsll((long long)m) - 1;
      if (lane == leader) atomicAdd(&gcnt[k], __popcll(m));
    }
  }
  __threadfence();
  __syncthreads();
  if (threadIdx.x == 0) {
    int t = atomicAdd(&gcnt[NE], 1);
    if (t == (int)gridDim.x - 1) {            // last block: prefix sum
      int acc = 0;
      for (int k = 0; k < NE; ++k) {
        int ck = atomicAdd(&gcnt[k], 0);      // coherent read
        offs[k] = acc; cur[k] = acc; acc += ck;
      }
      offs[NE] = acc;
    }
  }
}

// ----------------------------------------------------------- sort: scatter
__global__ __launch_bounds__(BLK) void scatter_kernel(
    const int* __restrict__ elem, int N,
    int* __restrict__ cur, int* __restrict__ order) {
  int n = blockIdx.x * BLK + threadIdx.x;
  if (n >= N) return;
  int e = elem[n];
  int lane = threadIdx.x & 63;
#pragma unroll
  for (int k = 0; k < NE; ++k) {
    if (e == k) {
      unsigned long long m = __ballot(1);
      int cnt = __popcll(m);
      int leader = __ffsll((long long)m) - 1;
      int base = 0;
      if (lane == leader) base = atomicAdd(&cur[k], cnt);
      base = __shfl(base, leader);
      int rank = __popcll(m & ((1ull << lane) - 1ull));
      order[base + rank] = n;
    }
  }
}

// ---- build + FULLY (u,v,w)-symmetrize + pack U(x)w tables (one dd/block)
__global__ __launch_bounds__(BLK) void table_kernel(
    const float* __restrict__ U3_0, const float* __restrict__ U2_0,
    const float* __restrict__ U1_0, const float* __restrict__ U3_1,
    const float* __restrict__ U2_1, const float* __restrict__ U1_1,
    const float* __restrict__ w3_0, const float* __restrict__ w2_0,
    const float* __restrict__ w1_0, const float* __restrict__ w3_1,
    const float* __restrict__ w2_1, const float* __restrict__ w1_1,
    float* __restrict__ table) {
  const int b = blockIdx.x;        // e*CCH + c
  const int dd = blockIdx.y;       // 0..3
  const int e = b / CCH, c = b % CCH;
  float* Tg = table + (size_t)b * TGSTR + dd * TSTR;
  __shared__ float Us[U3LDS];      // raw U3 slice [729*K3]
  __shared__ float U2s[324];       // raw U2 slice [81*K2]
  __shared__ float R3[729];        // rect T3
  __shared__ float R2[81];
  __shared__ float R1l[9];
  __shared__ float w3l[12], w2l[4];
  const int tid = threadIdx.x;
  const int d = dd - 1;
  const int K3 = (dd == 0) ? 10 : 12;
  const int K2 = (dd == 0) ? 3 : 4;

  if (dd == 0) {
    for (int i = tid; i < 7290; i += BLK) Us[i] = U3_0[i];
    for (int i = tid; i < 243; i += BLK)  U2s[i] = U2_0[i];
    if (tid < 10) w3l[tid] = w3_0[(e * 10 + tid) * CCH + c];
    else if (tid < 13) w2l[tid - 10] = w2_0[(e * 3 + (tid - 10)) * CCH + c];
    if (tid < 9) R1l[tid] = U1_0[tid] * w1_0[e * CCH + c];
  } else {
    for (int i = tid; i < 8748; i += BLK) Us[i] = U3_1[d * 8748 + i];
    for (int i = tid; i < 324; i += BLK)  U2s[i] = U2_1[d * 324 + i];
    if (tid < 12) w3l[tid] = w3_1[(e * 12 + tid) * CCH + c];
    else if (tid < 16) w2l[tid - 12] = w2_1[(e * 4 + (tid - 12)) * CCH + c];
    if (tid < 9) R1l[tid] = U1_1[d * 9 + tid] * w1_1[e * CCH + c];
  }
  __syncthreads();
  for (int r = tid; r < 729; r += BLK) {
    float acc = 0.f;
    for (int k = 0; k < K3; ++k) acc += Us[r * K3 + k] * w3l[k];
    R3[r] = acc;
  }
  for (int q = tid; q < 81; q += BLK) {
    float acc = 0.f;
    for (int k = 0; k < K2; ++k) acc += U2s[q * K2 + k] * w2l[k];
    R2[q] = acc;
  }
  __syncthreads();
  // pack: Horner consumption order. Per u: [T1s[u], then per v=u..8:
  //   [T2s[u][v], S3s[u][v][w] for w=v..8]].  Per-u size = (10-u)(11-u)/2.
  for (int i = tid; i < TSTR; i += BLK) {
    float val = 0.f;
    if (i < 219) {
      int rem = i, u = 0;
      while (rem >= (10 - u) * (11 - u) / 2) {
        rem -= (10 - u) * (11 - u) / 2; ++u;
      }
      if (rem == 0) {
        val = R1l[u];
      } else {
        rem -= 1;
        int v = u;
        while (rem >= 10 - v) { rem -= 10 - v; ++v; }
        if (rem == 0) {
          val = (u == v) ? R2[u * 9 + v] : R2[u * 9 + v] + R2[v * 9 + u];
        } else {
          int w = v + (rem - 1);
          if (u == v && v == w)
            val = R3[(u * 9 + u) * 9 + u];
          else if (u == v)
            val = R3[(u * 9 + u) * 9 + w] + R3[(u * 9 + w) * 9 + u] +
                  R3[(w * 9 + u) * 9 + u];
          else if (v == w)
            val = R3[(u * 9 + v) * 9 + v] + R3[(v * 9 + u) * 9 + v] +
                  R3[(v * 9 + v) * 9 + u];
          else
            val = R3[(u * 9 + v) * 9 + w] + R3[(u * 9 + w) * 9 + v] +
                  R3[(v * 9 + u) * 9 + w] + R3[(v * 9 + w) * 9 + u] +
                  R3[(w * 9 + u) * 9 + v] + R3[(w * 9 + v) * 9 + u];
        }
      }
    }
    Tg[i] = val;
  }
}

// --- symmetric contraction: triangular Horner over fully-sym table.
//     thread = 1 node x 1 channel; no LDS; cb via uniform s_load.
//     blockIdx.y = global chunk -> (e, segment) via offs (compact grid).
__global__ __launch_bounds__(BLK, 8) void contract_kernel(
    const float* __restrict__ feats, const float* __restrict__ table,
    const int* __restrict__ order, const int* __restrict__ offs,
    float* __restrict__ tmp, int NPAD) {
  const int c = blockIdx.x;                   // 0..127
  // map global chunk -> (element e, node range) ; wave-uniform
  int rem = blockIdx.y;
  int e = -1, pbase = 0, segend = 0;
#pragma unroll
  for (int k = 0; k < NE; ++k) {
    int st = offs[k], en = offs[k + 1];
    int nc = (en - st + BLK - 1) >> 8;        // chunks in segment k (BLK=256)
    if (e < 0) {
      if (rem < nc) { e = k; pbase = st + rem * BLK; segend = en; }
      else rem -= nc;
    }
  }
  if (e < 0) return;                          // slack chunk

  const int p = pbase + threadIdx.x;
  const bool valid = (p < segend);
  const int n = order[valid ? p : (segend - 1)];  // clamp: stay in-bounds

  float tf[LDIM];
  {
    const float* xp = feats + ((size_t)n * CCH + c) * LDIM;
#pragma unroll
    for (int q = 0; q < LDIM; ++q) tf[q] = xp[q];
  }

  const float* Tc = table + (size_t)(e * CCH + c) * TGSTR;

#pragma unroll 1
  for (int dd = 0; dd < 4; ++dd) {
    // wave-uniform address (blockIdx/dd only) -> s_load (SMEM path)
    const float* B = Tc + dd * TSTR;
    int idx = 0;                              // folds to constants on unroll
    float acc = 0.f;
#pragma unroll
    for (int u = 0; u < 9; ++u) {
      float inner = B[idx++];                 // T1s[u]
#pragma unroll
      for (int v = u; v < 9; ++v) {
        float Hv = B[idx++];                  // T2sym[u][v]
#pragma unroll
        for (int w = v; w < 9; ++w)
          Hv = fmaf(B[idx++], tf[w], Hv);
        inner = fmaf(Hv, tf[v], inner);
      }
      acc = fmaf(inner, tf[u], acc);
    }
    if (valid) tmp[((size_t)dd * CCH + c) * NPAD + p] = acc;
  }
}

// ------------- o3.Linear + residual: lane = node, W via wave-uniform s_load.
// block = 512 thr = 8 waves: wave = (gl 0..1, dd 0..3); covers 64 nodes x
// 32 c1 (quarter q = blockIdx.x&3) x 4 dd. Per ci: 1 coalesced A dword +
// 16 SGPR-operand FMA. Epilogue stages 128 floats/node in LDS, flushes as
// two contiguous spans (y0 slice, interleaved-y1 slice) + sc residual.
__global__ __launch_bounds__(512, 8) void linear_kernel(
    const float* __restrict__ tmp, const float* __restrict__ W0,
    const float* __restrict__ W1, const float* __restrict__ sc,
    const int* __restrict__ order, float* __restrict__ out, int N, int NPAD) {
  const int nc = blockIdx.x >> 2, q = blockIdx.x & 3;
  const int p0 = nc * 64;
  const int t = threadIdx.x;
  const int lane = t & 63;
  const int dd = __builtin_amdgcn_readfirstlane((t >> 6) & 3);
  const int gl = __builtin_amdgcn_readfirstlane(t >> 8);   // 0..1
  const int c1b = q * 32 + gl * 16;
  const int p = p0 + lane;
  const int pc = (p < N) ? p : (N - 1);

  __shared__ float SROW[64 * 132];    // [node][128 cols + 4 pad]

  const float* Wm = (dd == 0) ? W0 : W1;
  const float* Ap = tmp + (size_t)dd * CCH * NPAD + pc;    // lane-coalesced
  const float* Wb = Wm + c1b;                              // wave-uniform

  float acc[16];
#pragma unroll
  for (int k = 0; k < 16; ++k) acc[k] = 0.f;

#pragma unroll 4
  for (int ci = 0; ci < CCH; ++ci) {
    const float a = Ap[(size_t)ci * NPAD];
    const float* wr = Wb + ci * CCH;         // SGPR base -> s_load x16
#pragma unroll
    for (int k = 0; k < 16; ++k)
      acc[k] = fmaf(a, wr[k], acc[k]);
  }

  // stage scaled outputs: local col layout [0,32)=y0(c1-q*32),
  // [32,128)= (c1-q*32)*3 + (dd-1)
  const float s = 0.08838834764831843f;       // 1/sqrt(128)
  float* R = SROW + lane * 132;
  if (dd == 0) {
#pragma unroll
    for (int k = 0; k < 16; ++k) R[gl * 16 + k] = acc[k] * s;
  } else {
#pragma unroll
    for (int k = 0; k < 16; ++k)
      R[32 + (gl * 16 + k) * 3 + (dd - 1)] = acc[k] * s;
  }
  __syncthreads();

  // flush 64 rows x 32 float4; thread does 4; two contiguous global spans
#pragma unroll
  for (int kk = 0; kk < 4; ++kk) {
    const int i = t + kk * 512;
    const int row = i >> 5, c4 = i & 31;
    const int pr = p0 + row;
    if (pr < N) {
      const int n = order[pr];
      const int gcol = (c4 < 8) ? (q * 32 + c4 * 4)
                                : (CCH + q * 96 + (c4 - 8) * 4);
      float4 v = *(const float4*)(SROW + row * 132 + c4 * 4);
      const float4 sv = *(const float4*)(sc + (size_t)n * 512 + gcol);
      v.x += sv.x; v.y += sv.y; v.z += sv.z; v.w += sv.w;
      *(float4*)(out + (size_t)n * 512 + gcol) = v;
    }
  }
}

// -------------------------------------------------------------------- launch
extern "C" void kernel_launch(void* const* d_in, const int* in_sizes, int n_in,
                              void* d_out, int out_size, void* d_ws, size_t ws_size,
                              hipStream_t stream) {
  const float* feats = (const float*)d_in[0];
  const float* attrs = (const float*)d_in[1];
  const float* sc    = (const float*)d_in[2];
  const float* U3_0  = (const float*)d_in[3];
  const float* U2_0  = (const float*)d_in[4];
  const float* U1_0  = (const float*)d_in[5];
  const float* w3_0  = (const float*)d_in[6];
  const float* w2_0  = (const float*)d_in[7];
  const float* w1_0  = (const float*)d_in[8];
  const float* U3_1  = (const float*)d_in[9];
  const float* U2_1  = (const float*)d_in[10];
  const float* U1_1  = (const float*)d_in[11];
  const float* w3_1  = (const float*)d_in[12];
  const float* w2_1  = (const float*)d_in[13];
  const float* w1_1  = (const float*)d_in[14];
  const float* W0    = (const float*)d_in[15];
  const float* W1    = (const float*)d_in[16];

  const int N = in_sizes[0] / (CCH * LDIM);     // 10000
  const int NPAD = ((N + 15) & ~15) + 16;       // 10016

  // ws (floats): table[5*128*TGSTR] | tmp[4*C][NPAD] | order elem offs(8) cur(8) gcnt(8)
  float* table = (float*)d_ws;
  float* tmp   = table + (size_t)NE * CCH * TGSTR;
  int*   order = (int*)(tmp + (size_t)4 * CCH * NPAD);
  int*   elem  = order + N;
  int*   offs  = elem + N;
  int*   cur   = offs + 8;
  int*   gcnt  = cur + 8;                       // gcnt[0..4], gcnt[5]=done
  float* out   = (float*)d_out;

  hipMemsetAsync(gcnt, 0, 8 * sizeof(int), stream);

  const int nblk = (N + BLK - 1) / BLK;
  count_offs_kernel<<<dim3(nblk), dim3(BLK), 0, stream>>>(
      attrs, N, elem, gcnt, offs, cur);
  scatter_kernel<<<dim3(nblk), dim3(BLK), 0, stream>>>(elem, N, cur, order);

  table_kernel<<<dim3(NE * CCH, 4), dim3(BLK), 0, stream>>>(
      U3_0, U2_0, U1_0, U3_1, U2_1, U1_1,
      w3_0, w2_0, w1_0, w3_1, w2_1, w1_1, table);

  // compact chunk grid: sum over e of ceil(cnt_e/BLK) <= N/BLK + NE
  const int chunksMax = (N + BLK - 1) / BLK + NE;
  contract_kernel<<<dim3(CCH, chunksMax), dim3(BLK), 0, stream>>>(
      feats, table, order, offs, tmp, NPAD);

  const int lgrid = ((N + 63) / 64) * 4;        // 628
  linear_kernel<<<dim3(lgrid), dim3(512), 0, stream>>>(
      tmp, W0, W1, sc, order, out, N, NPAD);
}